// Round 2
// baseline (925.059 us; speedup 1.0000x reference)
//
#include <hip/hip_runtime.h>
#include <hip/hip_bf16.h>
#include <cstdint>
#include <cstddef>

typedef __hip_bfloat16 bf16;
typedef __bf16 bf16x8 __attribute__((ext_vector_type(8)));
typedef float f32x4 __attribute__((ext_vector_type(4)));

#define DEVFN static __device__ __forceinline__
#define BAR() asm volatile("s_barrier" ::: "memory")
#define VMCNT(n) asm volatile("s_waitcnt vmcnt(" #n ")" ::: "memory")

// async global->LDS, 16B per lane. LDS dest must be wave-uniform base + lane*16.
DEVFN void async16(const void* g, void* l) {
  __builtin_amdgcn_global_load_lds(
      (const __attribute__((address_space(1))) uint32_t*)g,
      (__attribute__((address_space(3))) uint32_t*)l, 16, 0, 0);
}

DEVFN float eluf(float v) { return v > 0.f ? v : expm1f(v); }
DEVFN float softplusf(float x) {
  return x > 0.f ? x + log1pf(expf(-x)) : log1pf(expf(x));
}

// ===========================================================================
// 256x256 8-phase GEMM core (T2+T3+T4+T5). BK=64, 8 waves = 2M x 4N, 512 thr.
// LDS (bf16 elems, 128 KiB total): buf b in [b*32768, (b+1)*32768):
//   A-half h at b*32768 + h*8192   (128 rows x 64 cols)
//   B-half h at b*32768 + 16384 + h*8192
// Swizzle: LDS slot (row, chunk s) holds global chunk s ^ (row&7)  (chunks of
// 8 bf16 = 16B). global_load_lds writes linearly, so the *global* source col
// is pre-swizzled; ds_read applies the same XOR. Per 16-lane group a fragment
// read hits all 8 chunk positions (2 lanes each) -> conflict-free (2-way).
// Schedule per iteration (2 K-tiles a=2j, b=2j+1; tile t lives in buf t&1):
//   ph0: read ALL A frags + B n0-1 of tile a; stage H(a+1,B1); MFMA Q(m0-3,n0-1)
//   ph1: read B n2-3;                 stage H(a+2,A0); MFMA Q(m0-3,n2-3)
//   ph2:                              stage H(a+2,A1); MFMA Q(m4-7,n0-1)
//   ph3:                              stage H(a+2,B0); MFMA; VMCNT(6)
//   ph4..ph7: same on tile b; stages H(a+2,B1), H(a+3,A0/A1/B0); VMCNT(6)
// vmcnt(6) = 3 half-tiles (2 loads each) stay in flight; never drained to 0
// in the main loop. Safety: every stage targets a region whose last ds_read
// happened in an earlier phase (barrier-separated).
// NOTE: NO min-waves launch bound on the 256^2 kernels. acc(128 VGPR) +
// A-frags(64) + B-frags(32) ~= 240 live VGPRs; a (512,2) bound capped at 128
// and spilled everything to scratch (round-1 regression: MfmaUtil 12%,
// +300 MB HBM). LDS=128 KiB already limits to 1 block/CU.
// ===========================================================================

DEVFN void stage_half(const bf16* p, int ld, bf16* reg, int tid) {
  async16(p, reg + tid * 8);
  async16(p + (size_t)64 * ld, reg + 4096 + tid * 8);
}

template <int PART>  // 0=A0 1=A1 2=B0 3=B1
DEVFN void stage_ht(const bf16* pA, const bf16* pB, int lda, int ldb,
                    bf16* lds, int tid, int t) {
  bf16* base = lds + (t & 1) * 32768;
  if constexpr (PART == 0)
    stage_half(pA + (size_t)t * 64, lda, base, tid);
  else if constexpr (PART == 1)
    stage_half(pA + (size_t)t * 64 + (size_t)128 * lda, lda, base + 8192, tid);
  else if constexpr (PART == 2)
    stage_half(pB + (size_t)t * 64, ldb, base + 16384, tid);
  else
    stage_half(pB + (size_t)t * 64 + (size_t)128 * ldb, ldb, base + 24576, tid);
}

template <int MB, int NB>
DEVFN void mfma8(f32x4 (&acc)[8][4], const bf16x8 (&af)[8][2],
                 const bf16x8 (&bv)[2][2]) {
#pragma unroll
  for (int mf = 0; mf < 4; ++mf)
#pragma unroll
    for (int nf = 0; nf < 2; ++nf) {
      acc[MB + mf][NB + nf] = __builtin_amdgcn_mfma_f32_16x16x32_bf16(
          af[MB + mf][0], bv[nf][0], acc[MB + mf][NB + nf], 0, 0, 0);
      acc[MB + mf][NB + nf] = __builtin_amdgcn_mfma_f32_16x16x32_bf16(
          af[MB + mf][1], bv[nf][1], acc[MB + mf][NB + nf], 0, 0, 0);
    }
}

// one K-tile = 4 phases. vmend: 6 -> VMCNT(6), 0 -> VMCNT(0), <0 -> none.
DEVFN void quad_phases(const bf16* Ab, const bf16* Bb, int cs0, int cs1,
                       f32x4 (&acc)[8][4], const bf16* pA, const bf16* pB,
                       int lda, int ldb, bf16* lds, int tid,
                       int tB1, int tN, bool st0, bool stN, int vmend) {
  bf16x8 af[8][2], b0[2][2], b1[2][2];
  // ---- P0: all 16 A frags + B n0-1
#pragma unroll
  for (int mf = 0; mf < 8; ++mf) {
    af[mf][0] = *(const bf16x8*)(Ab + mf * 1024 + cs0);
    af[mf][1] = *(const bf16x8*)(Ab + mf * 1024 + cs1);
  }
#pragma unroll
  for (int nf = 0; nf < 2; ++nf) {
    b0[nf][0] = *(const bf16x8*)(Bb + nf * 1024 + cs0);
    b0[nf][1] = *(const bf16x8*)(Bb + nf * 1024 + cs1);
  }
  if (st0) stage_ht<3>(pA, pB, lda, ldb, lds, tid, tB1);
  BAR();
  __builtin_amdgcn_s_setprio(1);
  mfma8<0, 0>(acc, af, b0);
  __builtin_amdgcn_s_setprio(0);
  BAR();
  // ---- P1: B n2-3
#pragma unroll
  for (int nf = 0; nf < 2; ++nf) {
    b1[nf][0] = *(const bf16x8*)(Bb + (2 + nf) * 1024 + cs0);
    b1[nf][1] = *(const bf16x8*)(Bb + (2 + nf) * 1024 + cs1);
  }
  if (stN) stage_ht<0>(pA, pB, lda, ldb, lds, tid, tN);
  BAR();
  __builtin_amdgcn_s_setprio(1);
  mfma8<0, 2>(acc, af, b1);
  __builtin_amdgcn_s_setprio(0);
  BAR();
  // ---- P2
  if (stN) stage_ht<1>(pA, pB, lda, ldb, lds, tid, tN);
  BAR();
  __builtin_amdgcn_s_setprio(1);
  mfma8<4, 0>(acc, af, b0);
  __builtin_amdgcn_s_setprio(0);
  BAR();
  // ---- P3
  if (stN) stage_ht<2>(pA, pB, lda, ldb, lds, tid, tN);
  BAR();
  __builtin_amdgcn_s_setprio(1);
  mfma8<4, 2>(acc, af, b1);
  __builtin_amdgcn_s_setprio(0);
  if (vmend == 0) { VMCNT(0); }
  else if (vmend > 0) { VMCNT(6); }
  BAR();
}

// pA/pB: per-thread staging base = X + (bt0 + (tid>>3))*ld + scol, where
// scol = ((tid&7) ^ ((tid>>3)&7)) * 8  (pre-swizzled global source column).
DEVFN void gemm256(const bf16* pA, const bf16* pB, int lda, int ldb, int NT,
                   bf16* lds, int tid, int wm, int wn, int quad, int l15,
                   f32x4 (&acc)[8][4]) {
  const int k7 = l15 & 7;
  const int cs0 = (quad ^ k7) * 8;        // kk=0 chunk
  const int cs1 = ((quad + 4) ^ k7) * 8;  // kk=1 chunk
  const bf16* Abase = lds + wm * 8192 + l15 * 64;
  const bf16* Bbase = lds + 16384 + (wn >> 1) * 8192 + ((wn & 1) * 64 + l15) * 64;
  // prologue: tile0 all 4 halves + tile1 A0,A1,B0  (14 loads in flight)
  stage_ht<0>(pA, pB, lda, ldb, lds, tid, 0);
  stage_ht<1>(pA, pB, lda, ldb, lds, tid, 0);
  stage_ht<2>(pA, pB, lda, ldb, lds, tid, 0);
  stage_ht<3>(pA, pB, lda, ldb, lds, tid, 0);
  stage_ht<0>(pA, pB, lda, ldb, lds, tid, 1);
  stage_ht<1>(pA, pB, lda, ldb, lds, tid, 1);
  stage_ht<2>(pA, pB, lda, ldb, lds, tid, 1);
  VMCNT(6);  // oldest 8 = all of tile0 landed
  BAR();
  const int NI = NT >> 1;
  for (int j = 0; j < NI; ++j) {
    const bool last = (j == NI - 1);
    const int a = 2 * j;
    quad_phases(Abase, Bbase, cs0, cs1, acc, pA, pB, lda, ldb, lds, tid,
                a + 1, a + 2, true, !last, last ? 0 : 6);
    quad_phases(Abase + 32768, Bbase + 32768, cs0, cs1, acc, pA, pB, lda, ldb,
                lds, tid, a + 2, a + 3, !last, !last, last ? -1 : 6);
  }
}

// ---------------------------------------------------------------------------
// BK=32 swizzled K-loop (kept for tail_k's bucketed z-head GEMM).
template <int NAH, int NBH, int NFB>
DEVFN void kloop32(const bf16* (&gA)[NAH], const bf16* (&gB)[NBH], bf16* As,
                   bf16* Bs, int tid, const bf16* aBase, const bf16* bBase,
                   int colsel, f32x4 (&acc)[4][NFB], int kiters) {
  for (int kt = 0; kt < kiters; ++kt) {
#pragma unroll
    for (int c = 0; c < NAH; ++c) async16(gA[c], As + c * 2048 + tid * 8);
#pragma unroll
    for (int c = 0; c < NBH; ++c) async16(gB[c], Bs + c * 2048 + tid * 8);
#pragma unroll
    for (int c = 0; c < NAH; ++c) gA[c] += 32;
#pragma unroll
    for (int c = 0; c < NBH; ++c) gB[c] += 32;
    __syncthreads();
    bf16x8 af[4], bfv[NFB];
#pragma unroll
    for (int r = 0; r < 4; ++r) af[r] = *(const bf16x8*)(aBase + r * 512 + colsel);
#pragma unroll
    for (int c = 0; c < NFB; ++c) bfv[c] = *(const bf16x8*)(bBase + c * 512 + colsel);
#pragma unroll
    for (int r = 0; r < 4; ++r)
#pragma unroll
      for (int c = 0; c < NFB; ++c)
        acc[r][c] = __builtin_amdgcn_mfma_f32_16x16x32_bf16(af[r], bfv[c], acc[r][c], 0, 0, 0);
    __syncthreads();
  }
}

DEVFN int swz_scol(int tid) { return (((tid & 3) ^ ((tid >> 3) & 3)) * 8); }
DEVFN int swz_colsel(int quad, int l15) { return ((quad ^ ((l15 >> 1) & 3)) * 8); }

// ---------------------------------------------------------------------------
// prep: all transposes/converts/bias-concat/bucket-bookkeeping in ONE launch
DEVFN void transpose_tile(const float* src, bf16* dst, int R, int C, int bx, int by) {
  __shared__ float tile[32][33];
  const int c0 = bx * 32, r0 = by * 32;
  const int tx = threadIdx.x & 31, ty = threadIdx.x >> 5;
#pragma unroll
  for (int rr = ty; rr < 32; rr += 8)
    tile[rr][tx] = src[(size_t)(r0 + rr) * C + c0 + tx];
  __syncthreads();
#pragma unroll
  for (int rr = ty; rr < 32; rr += 8)
    dst[(size_t)(c0 + rr) * R + r0 + tx] = __float2bfloat16(tile[tx][rr]);
}

__global__ __launch_bounds__(256) void prep_all_k(
    const float* __restrict__ x, bf16* __restrict__ xb,
    const float* __restrict__ yw0, const float* __restrict__ dw0,
    const float* __restrict__ zw0, const float* __restrict__ tw0,
    bf16* __restrict__ BtL1,
    const float* __restrict__ yw1, const float* __restrict__ dw1,
    const float* __restrict__ zw1, bf16* __restrict__ BtL2,
    const float* __restrict__ tw1, bf16* __restrict__ tw1t,
    const float* __restrict__ zhW, bf16* __restrict__ zhWt,
    const float* __restrict__ yb0, const float* __restrict__ db0,
    const float* __restrict__ zb0, const float* __restrict__ tb0,
    const float* __restrict__ yb1, const float* __restrict__ db1,
    const float* __restrict__ zb1,
    float* __restrict__ biasAll, float* __restrict__ r0All,
    float* __restrict__ r1All, float* __restrict__ biasL2,
    const int* __restrict__ t, int* __restrict__ cnt, int* __restrict__ seg,
    int* __restrict__ rank, int* __restrict__ sids) {
  int l = blockIdx.x;
  if (l < 8192) {  // x fp32 -> bf16, 8 elems/thread
    size_t i = ((size_t)l * 256 + threadIdx.x) * 8;
    float4 v0 = *(const float4*)(x + i);
    float4 v1 = *(const float4*)(x + i + 4);
    union { bf16 h[8]; uint4 u; } o;
    o.h[0] = __float2bfloat16(v0.x); o.h[1] = __float2bfloat16(v0.y);
    o.h[2] = __float2bfloat16(v0.z); o.h[3] = __float2bfloat16(v0.w);
    o.h[4] = __float2bfloat16(v1.x); o.h[5] = __float2bfloat16(v1.y);
    o.h[6] = __float2bfloat16(v1.z); o.h[7] = __float2bfloat16(v1.w);
    *(uint4*)(xb + i) = o.u;
    return;
  }
  l -= 8192;
  if (l < 4096) {  // BtL1: {yw0,dw0,zw0[2:],tw0} transposed
    int z = l >> 10, rem = l & 1023, bx = rem & 31, by = rem >> 5;
    const float* src = (z == 0) ? yw0 : (z == 1) ? dw0 : (z == 2) ? zw0 + 2048 : tw0;
    int C = (z == 3) ? 256 : 1024;
    if (bx * 32 < C)
      transpose_tile(src, BtL1 + (size_t)z * 1024 * 1024, 1024, C, bx, by);
    return;
  }
  l -= 4096;
  if (l < 3072) {  // BtL2: {yw1,dw1,zw1} transposed
    int z = l >> 10, rem = l & 1023, bx = rem & 31, by = rem >> 5;
    const float* src = (z == 0) ? yw1 : (z == 1) ? dw1 : zw1;
    transpose_tile(src, BtL2 + (size_t)z * 1024 * 1024, 1024, 1024, bx, by);
    return;
  }
  l -= 3072;
  if (l < 64) {  // tw1t
    transpose_tile(tw1, tw1t, 256, 256, l & 7, l >> 3);
    return;
  }
  l -= 64;
  if (l < 3584) {  // zhWt: 7 x [1024][512] -> [512][1024]
    int z = l >> 9, rem = l & 511, bx = rem & 15, by = rem >> 4;
    transpose_tile(zhW + (size_t)z * 1024 * 512, zhWt + (size_t)z * 512 * 1024,
                   1024, 512, bx, by);
    return;
  }
  l -= 3584;
  if (l < 13) {  // bias / rank-2 concat
    int i = l * 256 + threadIdx.x;
    if (i >= 3328) return;
    float b;
    if (i < 1024) b = yb0[i];
    else if (i < 2048) b = db0[i - 1024];
    else if (i < 3072) b = zb0[i - 2048];
    else b = tb0[i - 3072];
    biasAll[i] = b;
    bool inz = (i >= 2048 && i < 3072);
    r0All[i] = inz ? zw0[i - 2048] : 0.f;
    r1All[i] = inz ? zw0[1024 + (i - 2048)] : 0.f;
    if (i < 3072)
      biasL2[i] = (i < 1024) ? yb1[i] : (i < 2048) ? db1[i - 1024] : zb1[i - 2048];
    return;
  }
  {  // bucket bookkeeping: single block, 256 threads x 64 items
    __shared__ int h[8], sseg[8];
    const int tid = threadIdx.x;
    if (tid < 8) h[tid] = 0;
    __syncthreads();
    const int base = tid * 64;
    int lc[7] = {0, 0, 0, 0, 0, 0, 0};
    for (int i = 0; i < 64; ++i) lc[t[base + i]]++;
    int myoff[7];
#pragma unroll
    for (int k = 0; k < 7; ++k) myoff[k] = atomicAdd(&h[k], lc[k]);
    __syncthreads();
    if (tid == 0) {
      int s = 0;
      for (int k = 0; k < 7; ++k) { sseg[k] = s; s += h[k]; }
      sseg[7] = s;
    }
    __syncthreads();
    if (tid < 7) { cnt[tid] = h[tid]; seg[tid] = sseg[tid]; }
    if (tid == 7) seg[7] = sseg[7];
    int cur[7];
#pragma unroll
    for (int k = 0; k < 7; ++k) cur[k] = sseg[k] + myoff[k];
    for (int i = 0; i < 64; ++i) {
      int b = base + i, k = t[b];
      int r = cur[k]++;
      rank[b] = r;
      sids[r] = b;
    }
  }
}

// ---------------------------------------------------------------------------
// fused layer-1: [16384,1024] x [1024,3328] -> {a1y,a1d,a1z,ht1}
// 256x256 8-phase core; XCD-contiguous m-bands (832 = 8 xcd x 8 m x 13 n).
__global__ __launch_bounds__(512, 1) void gemm_l1_k(
    const bf16* __restrict__ A, const bf16* __restrict__ Bt,
    const float* __restrict__ biasAll, const float* __restrict__ r0All,
    const float* __restrict__ r1All, const float* __restrict__ yv,
    const float* __restrict__ dv, bf16* __restrict__ a1y,
    bf16* __restrict__ a1d, bf16* __restrict__ a1z, bf16* __restrict__ ht1) {
  __shared__ bf16 lds[65536];  // 128 KiB
  const int tid = threadIdx.x, lane = tid & 63, wid = tid >> 6;
  const int wm = wid >> 2, wn = wid & 3, quad = lane >> 4, l15 = lane & 15;
  const int id = blockIdx.x;
  const int xcd = id & 7, lid = id >> 3;             // lid in [0,104)
  const int mt = xcd * 8 + (lid & 7), nt = lid >> 3; // mt<64, nt<13
  const int bm0 = mt * 256, bn0 = nt * 256;
  const int srow = tid >> 3, scol = ((tid & 7) ^ ((tid >> 3) & 7)) * 8;
  const bf16* pA = A + (size_t)(bm0 + srow) * 1024 + scol;
  const bf16* pB = Bt + (size_t)(bn0 + srow) * 1024 + scol;
  f32x4 acc[8][4] = {};
  gemm256(pA, pB, 1024, 1024, 16, lds, tid, wm, wn, quad, l15, acc);

  const int g = nt >> 2;
  bf16* dst = (g == 0) ? a1y : (g == 1) ? a1d : (g == 2) ? a1z : ht1;
  const int ldc = (g == 3) ? 256 : 1024;
  const int colb = bn0 - g * 1024;
  float bv[4], z0[4], z1[4];
#pragma unroll
  for (int nf = 0; nf < 4; ++nf) {
    int gn = bn0 + wn * 64 + nf * 16 + l15;
    bv[nf] = biasAll[gn]; z0[nf] = r0All[gn]; z1[nf] = r1All[gn];
  }
#pragma unroll
  for (int mf = 0; mf < 8; ++mf) {
    const int rbase = bm0 + wm * 128 + mf * 16 + quad * 4;
    const float4 y4 = *(const float4*)(yv + rbase);
    const float4 d4 = *(const float4*)(dv + rbase);
#pragma unroll
    for (int q = 0; q < 4; ++q) {
      const float yy = (&y4.x)[q], dd = (&d4.x)[q];
      const size_t ro = (size_t)(rbase + q) * ldc + colb + wn * 64;
#pragma unroll
      for (int nf = 0; nf < 4; ++nf) {
        float v = acc[mf][nf][q] + bv[nf] + yy * z0[nf] + dd * z1[nf];
        dst[ro + nf * 16 + l15] = __float2bfloat16(eluf(v));
      }
    }
  }
}

// fused layer-2 + t-layer-2: blocks [0,768) = y1|d1|z1 (K=1024, XCD bands),
// blocks [768,832) = t1 (K=256). hz rows written permuted via rank[].
__global__ __launch_bounds__(512, 1) void gemm_l2t_k(
    const bf16* __restrict__ a1y, const bf16* __restrict__ a1d,
    const bf16* __restrict__ a1z, const bf16* __restrict__ ht1,
    const bf16* __restrict__ BtL2, const bf16* __restrict__ tw1t,
    const float* __restrict__ biasL2, const float* __restrict__ tb1,
    bf16* __restrict__ hyd, bf16* __restrict__ hzg, bf16* __restrict__ ht2,
    const int* __restrict__ rank) {
  __shared__ bf16 lds[65536];
  const int tid = threadIdx.x, lane = tid & 63, wid = tid >> 6;
  const int wm = wid >> 2, wn = wid & 3, quad = lane >> 4, l15 = lane & 15;
  const int id = blockIdx.x;
  int bm0, bn0, Ka, g;
  const bf16 *Aptr, *Bptr;
  if (id < 768) {
    const int xcd = id & 7, lid = id >> 3;             // lid in [0,96)
    const int mt = xcd * 8 + (lid & 7), nt = lid >> 3; // mt<64, nt<12
    bm0 = mt * 256; bn0 = nt * 256; Ka = 1024;
    g = nt >> 2;
    Aptr = (g == 0) ? a1y : (g == 1) ? a1d : a1z;
    Bptr = BtL2;
  } else {
    const int local = id - 768;  // [0,64)
    bm0 = local * 256; bn0 = 0; Ka = 256;
    g = 3; Aptr = ht1; Bptr = tw1t;
  }
  const int srow = tid >> 3, scol = ((tid & 7) ^ ((tid >> 3) & 7)) * 8;
  const bf16* pA = Aptr + (size_t)(bm0 + srow) * Ka + scol;
  const bf16* pB = Bptr + (size_t)(bn0 + srow) * Ka + scol;
  f32x4 acc[8][4] = {};
  gemm256(pA, pB, Ka, Ka, Ka >> 6, lds, tid, wm, wn, quad, l15, acc);

  const float* bias = (g == 3) ? tb1 : biasL2;
  float bv[4];
#pragma unroll
  for (int nf = 0; nf < 4; ++nf) bv[nf] = bias[bn0 + wn * 64 + nf * 16 + l15];
#pragma unroll
  for (int mf = 0; mf < 8; ++mf) {
#pragma unroll
    for (int q = 0; q < 4; ++q) {
      const int gm = bm0 + wm * 128 + mf * 16 + quad * 4 + q;
      bf16* dst; size_t rowoff;
      if (g == 2) { dst = hzg; rowoff = (size_t)rank[gm] * 1024 + (size_t)(bn0 - 2048); }
      else if (g == 3) { dst = ht2; rowoff = (size_t)gm * 256; }
      else { dst = hyd; rowoff = (size_t)gm * 2048 + bn0; }
#pragma unroll
      for (int nf = 0; nf < 4; ++nf) {
        float v = acc[mf][nf][q] + bv[nf];
        dst[rowoff + wn * 64 + nf * 16 + l15] = __float2bfloat16(eluf(v));
      }
    }
  }
}

// ---------------------------------------------------------------------------
// merged tail: z-head bucketed GEMM (blocks < ZB) + y/d heads + t-logits.
#define ZMT 28  // max m-tiles per bucket (covers 3584 rows; mean 2341, +27 sigma)
#define ZB (7 * ZMT * 8)
__global__ __launch_bounds__(256) void tail_k(
    const bf16* __restrict__ hzg, const bf16* __restrict__ zhWt,
    const float* __restrict__ zhb, const int* __restrict__ seg,
    const int* __restrict__ cnts, const int* __restrict__ sids,
    const bf16* __restrict__ hyd, const bf16* __restrict__ ht2,
    const int* __restrict__ t, const float* __restrict__ yhW,
    const float* __restrict__ yhb, const float* __restrict__ dhW,
    const float* __restrict__ dhb, const float* __restrict__ tw2,
    const float* __restrict__ tb2, float* __restrict__ out) {
  __shared__ bf16 As[128 * 32];  // 8 KB
  __shared__ bf16 Bs[64 * 32];   // 4 KB
  const int tid = threadIdx.x, lane = tid & 63, wid = tid >> 6;
  const int wv = wid, quad = lane >> 4, l15 = lane & 15;
  if (blockIdx.x < ZB) {
    const int kb = blockIdx.x / (ZMT * 8);
    const int r = blockIdx.x % (ZMT * 8);
    const int cnt = cnts[kb];
    const int bm0 = (r >> 3) * 128;
    if (bm0 >= cnt) return;
    const int n0 = (r & 7) * 64;
    const int wm = wid >> 1, wn = wid & 1;
    const int base = seg[kb];
    const int sr = tid >> 2, scol = swz_scol(tid);
    const bf16* gA[2];
    const bf16* gB[1];
#pragma unroll
    for (int c = 0; c < 2; ++c) {
      int rr = bm0 + c * 64 + sr;
      if (rr >= cnt) rr = cnt - 1;
      gA[c] = hzg + (size_t)(base + rr) * 1024 + scol;
    }
    gB[0] = zhWt + (size_t)kb * 512 * 1024 + (size_t)(n0 + sr) * 1024 + scol;
    const bf16* aBase = &As[(wm * 64 + l15) * 32];
    const bf16* bBase = &Bs[(wn * 32 + l15) * 32];
    const int colsel = swz_colsel(quad, l15);
    f32x4 acc[4][2] = {};
    kloop32<2, 1, 2>(gA, gB, As, Bs, tid, aBase, bBase, colsel, acc, 32);
    const float* bias = zhb + (size_t)kb * 512;
    float bv[2]; int gnn[2];
#pragma unroll
    for (int c = 0; c < 2; ++c) {
      gnn[c] = n0 + wn * 32 + c * 16 + l15;
      bv[c] = bias[gnn[c]];
    }
#pragma unroll
    for (int r2 = 0; r2 < 4; ++r2)
#pragma unroll
      for (int q = 0; q < 4; ++q) {
        int lm = bm0 + wm * 64 + r2 * 16 + quad * 4 + q;
        if (lm < cnt) {
          int gm = sids[base + lm];
          size_t ob = (size_t)gm * 523 + 11;
#pragma unroll
          for (int c = 0; c < 2; ++c) {
            float v = acc[r2][c][q] + bv[c];
            int n = gnn[c];
            out[ob + n] = (n < 256) ? fminf(fmaxf(v, -100.f), 100.f)
                                    : fminf(softplusf(v) + 0.001f, 100.f);
          }
        }
      }
    return;
  }
  const int hid = blockIdx.x - ZB;
  if (hid < 4096) {  // y/d heads
    const int b = hid * 4 + wv;
    const int tb = t[b];
    const float* yW = yhW + (size_t)tb * 2048;
    const float* dW = dhW + (size_t)tb * 2048;
    float s0 = 0.f, s1 = 0.f, s2 = 0.f, s3 = 0.f;
    for (int i = lane; i < 1024; i += 64) {
      float a = __bfloat162float(hyd[(size_t)b * 2048 + i]);
      float c = __bfloat162float(hyd[(size_t)b * 2048 + 1024 + i]);
      s0 += a * yW[2 * i]; s1 += a * yW[2 * i + 1];
      s2 += c * dW[2 * i]; s3 += c * dW[2 * i + 1];
    }
#pragma unroll
    for (int off = 32; off > 0; off >>= 1) {
      s0 += __shfl_down(s0, off); s1 += __shfl_down(s1, off);
      s2 += __shfl_down(s2, off); s3 += __shfl_down(s3, off);
    }
    if (lane == 0) {
      size_t o = (size_t)b * 523;
      out[o + 7] = fminf(fmaxf(s0 + yhb[tb * 2], -1e6f), 1e6f);
      out[o + 8] = fminf(softplusf(s1 + yhb[tb * 2 + 1]) + 1e-3f, 1e6f);
      out[o + 9] = fminf(fmaxf(s2 + dhb[tb * 2], -1e6f), 1e6f);
      out[o + 10] = fminf(softplusf(s3 + dhb[tb * 2 + 1]) + 1e-3f, 1e6f);
    }
  } else {  // t logits
    const int b = (hid - 4096) * 4 + wv;
    float h[4];
#pragma unroll
    for (int j = 0; j < 4; ++j)
      h[j] = __bfloat162float(ht2[(size_t)b * 256 + lane * 4 + j]);
    float pp[7];
#pragma unroll
    for (int kk = 0; kk < 7; ++kk) {
      float s = 0.f;
#pragma unroll
      for (int j = 0; j < 4; ++j) s += h[j] * tw2[(lane * 4 + j) * 7 + kk];
      pp[kk] = s;
    }
#pragma unroll
    for (int kk = 0; kk < 7; ++kk)
#pragma unroll
      for (int off = 32; off > 0; off >>= 1) pp[kk] += __shfl_down(pp[kk], off);
    if (lane == 0) {
#pragma unroll
      for (int kk = 0; kk < 7; ++kk) {
        float v = eluf(pp[kk] + tb2[kk]);
        out[(size_t)b * 523 + kk] = fminf(fmaxf(v, -10.f), 10.f);
      }
    }
  }
}

// ---------------------------------------------------------------------------
extern "C" void kernel_launch(void* const* d_in, const int* in_sizes, int n_in,
                              void* d_out, int out_size, void* d_ws, size_t ws_size,
                              hipStream_t stream) {
  const float* x   = (const float*)d_in[0];
  const int*   t   = (const int*)d_in[1];
  const float* yv  = (const float*)d_in[2];
  const float* dv  = (const float*)d_in[3];
  const float* tw0 = (const float*)d_in[4];
  const float* tb0 = (const float*)d_in[5];
  const float* tw1 = (const float*)d_in[6];
  const float* tb1 = (const float*)d_in[7];
  const float* tw2 = (const float*)d_in[8];
  const float* tb2 = (const float*)d_in[9];
  const float* yw0 = (const float*)d_in[10];
  const float* yb0 = (const float*)d_in[11];
  const float* yw1 = (const float*)d_in[12];
  const float* yb1 = (const float*)d_in[13];
  const float* yhW = (const float*)d_in[14];
  const float* yhb = (const float*)d_in[15];
  const float* dw0 = (const float*)d_in[16];
  const float* db0 = (const float*)d_in[17];
  const float* dw1 = (const float*)d_in[18];
  const float* db1 = (const float*)d_in[19];
  const float* dhW = (const float*)d_in[20];
  const float* dhb = (const float*)d_in[21];
  const float* zw0 = (const float*)d_in[22];
  const float* zb0 = (const float*)d_in[23];
  const float* zw1 = (const float*)d_in[24];
  const float* zb1 = (const float*)d_in[25];
  const float* zhW = (const float*)d_in[26];
  const float* zhb = (const float*)d_in[27];
  float* out = (float*)d_out;

  const int B = 16384;
  char* p = (char*)d_ws;
  auto take = [&](size_t bytes) {
    char* r = p;
    p += (bytes + 255) & ~(size_t)255;
    return r;
  };
  bf16*  BtL1    = (bf16*)take((size_t)3328 * 1024 * 2);
  bf16*  BtL2    = (bf16*)take((size_t)3072 * 1024 * 2);
  bf16*  tw1t    = (bf16*)take((size_t)256 * 256 * 2);
  bf16*  zhWt    = (bf16*)take((size_t)7 * 512 * 1024 * 2);
  float* biasAll = (float*)take(3328 * 4);
  float* r0All   = (float*)take(3328 * 4);
  float* r1All   = (float*)take(3328 * 4);
  float* biasL2  = (float*)take(3072 * 4);
  int*   cnt     = (int*)take(8 * 4);
  int*   seg     = (int*)take(8 * 4);
  int*   rank    = (int*)take((size_t)B * 4);
  int*   sids    = (int*)take((size_t)B * 4);
  bf16*  xb      = (bf16*)take((size_t)B * 1024 * 2);  // reused as hzg after L1
  bf16*  a1y     = (bf16*)take((size_t)B * 1024 * 2);
  bf16*  a1d     = (bf16*)take((size_t)B * 1024 * 2);
  bf16*  a1z     = (bf16*)take((size_t)B * 1024 * 2);
  bf16*  ht1     = (bf16*)take((size_t)B * 256 * 2);
  bf16*  hyd     = (bf16*)take((size_t)B * 2048 * 2);
  bf16*  ht2     = (bf16*)take((size_t)B * 256 * 2);
  bf16*  hzg     = xb;

  prep_all_k<<<19022, 256, 0, stream>>>(x, xb, yw0, dw0, zw0, tw0, BtL1,
                                        yw1, dw1, zw1, BtL2, tw1, tw1t, zhW, zhWt,
                                        yb0, db0, zb0, tb0, yb1, db1, zb1,
                                        biasAll, r0All, r1All, biasL2,
                                        t, cnt, seg, rank, sids);
  gemm_l1_k<<<832, 512, 0, stream>>>(xb, BtL1, biasAll, r0All, r1All,
                                     yv, dv, a1y, a1d, a1z, ht1);
  gemm_l2t_k<<<832, 512, 0, stream>>>(a1y, a1d, a1z, ht1, BtL2, tw1t,
                                      biasL2, tb1, hyd, hzg, ht2, rank);
  tail_k<<<ZB + 8192, 256, 0, stream>>>(hzg, zhWt, zhb, seg, cnt, sids,
                                        hyd, ht2, t, yhW, yhb, dhW, dhb,
                                        tw2, tb2, out);
}

// Round 3
// 673.394 us; speedup vs baseline: 1.3737x; 1.3737x over previous
//
#include <hip/hip_runtime.h>
#include <hip/hip_bf16.h>
#include <cstdint>
#include <cstddef>

typedef __hip_bfloat16 bf16;
typedef __bf16 bf16x8 __attribute__((ext_vector_type(8)));
typedef float f32x4 __attribute__((ext_vector_type(4)));

#define DEVFN static __device__ __forceinline__
#define BAR() asm volatile("s_barrier" ::: "memory")
#define VMCNT(n) asm volatile("s_waitcnt vmcnt(" #n ")" ::: "memory")

// async global->LDS, 16B per lane. LDS dest must be wave-uniform base + lane*16.
DEVFN void async16(const void* g, void* l) {
  __builtin_amdgcn_global_load_lds(
      (const __attribute__((address_space(1))) uint32_t*)g,
      (__attribute__((address_space(3))) uint32_t*)l, 16, 0, 0);
}

DEVFN float eluf(float v) { return v > 0.f ? v : expm1f(v); }
DEVFN float softplusf(float x) {
  return x > 0.f ? x + log1pf(expf(-x)) : log1pf(expf(x));
}

// ===========================================================================
// 256x256 8-phase GEMM core (T2+T3+T4+T5). BK=64, 8 waves = 2M x 4N, 512 thr.
// LDS (bf16 elems, 128 KiB total): buf b in [b*32768, (b+1)*32768):
//   A-half h at b*32768 + h*8192   (128 rows x 64 cols)
//   B-half h at b*32768 + 16384 + h*8192
// Swizzle: LDS slot (row, chunk s) holds global chunk s ^ (row&7)  (chunks of
// 8 bf16 = 16B); staged via pre-swizzled GLOBAL source col, read with same XOR.
//
// REGISTER BUDGET (the round-1/2 lesson): LDS=128KiB forces 1 block/CU ->
// 2 waves/SIMD -> hard 256 unified regs/wave (128 arch + 128 AGPR for acc).
// Fragment liveness must fit the 128 arch side. So A-frags are read in TWO
// waves: af_lo(m0-3) at P0, af_hi(m4-7) at P2 REUSING the same 32 VGPRs.
// Max live frags = af[4][2](32) + b0(16) + b1(16) = 64 VGPR. Reading all 16
// A-frags in P0 (rounds 1-2) forced ~96 live + addrs > 128 -> scratch spill
// (+300 MB HBM, MfmaUtil 12%).
//
// Phase plan per K-tile t (buf = t&1):
//   P0: read af_lo + b0; stage B1(t+1); BAR; MFMA (m0-3,n0-1); BAR
//   P1: read b1;         stage A1(t+1); BAR; MFMA (m0-3,n2-3); BAR
//   P2: read af_hi;      stage B0(t+2); BAR; MFMA (m4-7,n0-1); BAR
//   P3:                  stage A0(t+2); BAR; MFMA (m4-7,n2-3); VMCNT(4); BAR
// Stage-safety: B-half reads of buf(t) drain by P1's lgkm-wait -> B0(t+2)
// stage at P2 is 1 barrier later; A-half reads drain by P2 -> A0(t+2) at P3.
// B1/A1(t+1) go to the OTHER buffer (read through quad t-1) -> P0/P1 safe.
// vmcnt(4) = 2 stage-pairs (P2,P3 of this quad) stay in flight; each tile's
// 4 halves are confirmed landed by the vmcnt(4)+BAR at the end of the
// preceding quad. Final quads drain with VMCNT(0).
// ===========================================================================

DEVFN void stage_half(const bf16* p, int ld, bf16* reg, int tid) {
  async16(p, reg + tid * 8);
  async16(p + (size_t)64 * ld, reg + 4096 + tid * 8);
}

template <int PART>  // 0=A0 1=A1 2=B0 3=B1
DEVFN void stage_ht(const bf16* pA, const bf16* pB, int lda, int ldb,
                    bf16* lds, int tid, int t) {
  bf16* base = lds + (t & 1) * 32768;
  if constexpr (PART == 0)
    stage_half(pA + (size_t)t * 64, lda, base, tid);
  else if constexpr (PART == 1)
    stage_half(pA + (size_t)t * 64 + (size_t)128 * lda, lda, base + 8192, tid);
  else if constexpr (PART == 2)
    stage_half(pB + (size_t)t * 64, ldb, base + 16384, tid);
  else
    stage_half(pB + (size_t)t * 64 + (size_t)128 * ldb, ldb, base + 24576, tid);
}

template <int MB, int NB>
DEVFN void mfma4(f32x4 (&acc)[8][4], const bf16x8 (&af)[4][2],
                 const bf16x8 (&bv)[2][2]) {
#pragma unroll
  for (int mf = 0; mf < 4; ++mf)
#pragma unroll
    for (int nf = 0; nf < 2; ++nf) {
      acc[MB + mf][NB + nf] = __builtin_amdgcn_mfma_f32_16x16x32_bf16(
          af[mf][0], bv[nf][0], acc[MB + mf][NB + nf], 0, 0, 0);
      acc[MB + mf][NB + nf] = __builtin_amdgcn_mfma_f32_16x16x32_bf16(
          af[mf][1], bv[nf][1], acc[MB + mf][NB + nf], 0, 0, 0);
    }
}

// one K-tile = 4 phases. t = tile index (for staging). vmend: 4 / 0 / -1(none)
DEVFN void quad_phases(const bf16* Ab, const bf16* Bb, int cs0, int cs1,
                       f32x4 (&acc)[8][4], const bf16* pA, const bf16* pB,
                       int lda, int ldb, bf16* lds, int tid,
                       int t, bool st1, bool st2, int vmend) {
  bf16x8 af[4][2], b0[2][2], b1[2][2];
  // ---- P0: af_lo (m0-3) + b0 (n0-1)
#pragma unroll
  for (int mf = 0; mf < 4; ++mf) {
    af[mf][0] = *(const bf16x8*)(Ab + mf * 1024 + cs0);
    af[mf][1] = *(const bf16x8*)(Ab + mf * 1024 + cs1);
  }
#pragma unroll
  for (int nf = 0; nf < 2; ++nf) {
    b0[nf][0] = *(const bf16x8*)(Bb + nf * 1024 + cs0);
    b0[nf][1] = *(const bf16x8*)(Bb + nf * 1024 + cs1);
  }
  if (st1) stage_ht<3>(pA, pB, lda, ldb, lds, tid, t + 1);
  BAR();
  __builtin_amdgcn_s_setprio(1);
  mfma4<0, 0>(acc, af, b0);
  __builtin_amdgcn_s_setprio(0);
  BAR();
  // ---- P1: b1 (n2-3)
#pragma unroll
  for (int nf = 0; nf < 2; ++nf) {
    b1[nf][0] = *(const bf16x8*)(Bb + (2 + nf) * 1024 + cs0);
    b1[nf][1] = *(const bf16x8*)(Bb + (2 + nf) * 1024 + cs1);
  }
  if (st1) stage_ht<1>(pA, pB, lda, ldb, lds, tid, t + 1);
  BAR();
  __builtin_amdgcn_s_setprio(1);
  mfma4<0, 2>(acc, af, b1);
  __builtin_amdgcn_s_setprio(0);
  BAR();
  // ---- P2: af_hi (m4-7), reuse af registers
#pragma unroll
  for (int mf = 0; mf < 4; ++mf) {
    af[mf][0] = *(const bf16x8*)(Ab + (4 + mf) * 1024 + cs0);
    af[mf][1] = *(const bf16x8*)(Ab + (4 + mf) * 1024 + cs1);
  }
  if (st2) stage_ht<2>(pA, pB, lda, ldb, lds, tid, t + 2);
  BAR();
  __builtin_amdgcn_s_setprio(1);
  mfma4<4, 0>(acc, af, b0);
  __builtin_amdgcn_s_setprio(0);
  BAR();
  // ---- P3
  if (st2) stage_ht<0>(pA, pB, lda, ldb, lds, tid, t + 2);
  BAR();
  __builtin_amdgcn_s_setprio(1);
  mfma4<4, 2>(acc, af, b1);
  __builtin_amdgcn_s_setprio(0);
  if (vmend == 0) { VMCNT(0); }
  else if (vmend > 0) { VMCNT(4); }
  BAR();
}

// pA/pB: per-thread staging base = X + (bt0 + (tid>>3))*ld + scol, where
// scol = ((tid&7) ^ ((tid>>3)&7)) * 8  (pre-swizzled global source column).
DEVFN void gemm256(const bf16* pA, const bf16* pB, int lda, int ldb, int NT,
                   bf16* lds, int tid, int wm, int wn, int quad, int l15,
                   f32x4 (&acc)[8][4]) {
  const int k7 = l15 & 7;
  const int cs0 = (quad ^ k7) * 8;        // kk=0 chunk
  const int cs1 = ((quad + 4) ^ k7) * 8;  // kk=1 chunk
  const bf16* Abase = lds + wm * 8192 + l15 * 64;
  const bf16* Bbase = lds + 16384 + (wn >> 1) * 8192 + ((wn & 1) * 64 + l15) * 64;
  // prologue: tile0 all 4 halves + tile1 B0,A0 (12 loads in flight)
  stage_ht<0>(pA, pB, lda, ldb, lds, tid, 0);
  stage_ht<1>(pA, pB, lda, ldb, lds, tid, 0);
  stage_ht<2>(pA, pB, lda, ldb, lds, tid, 0);
  stage_ht<3>(pA, pB, lda, ldb, lds, tid, 0);
  stage_ht<2>(pA, pB, lda, ldb, lds, tid, 1);
  stage_ht<0>(pA, pB, lda, ldb, lds, tid, 1);
  VMCNT(4);  // tile0's 4 halves landed; B0(1),A0(1) in flight
  BAR();
  const int NI = NT >> 1;
  for (int j = 0; j < NI; ++j) {
    const bool last = (j == NI - 1);
    const int a = 2 * j;
    quad_phases(Abase, Bbase, cs0, cs1, acc, pA, pB, lda, ldb, lds, tid,
                a, true, !last, last ? 0 : 4);
    quad_phases(Abase + 32768, Bbase + 32768, cs0, cs1, acc, pA, pB, lda, ldb,
                lds, tid, a + 1, !last, !last, last ? -1 : 4);
  }
}

// ---------------------------------------------------------------------------
// BK=32 swizzled K-loop (kept for tail_k's bucketed z-head GEMM).
template <int NAH, int NBH, int NFB>
DEVFN void kloop32(const bf16* (&gA)[NAH], const bf16* (&gB)[NBH], bf16* As,
                   bf16* Bs, int tid, const bf16* aBase, const bf16* bBase,
                   int colsel, f32x4 (&acc)[4][NFB], int kiters) {
  for (int kt = 0; kt < kiters; ++kt) {
#pragma unroll
    for (int c = 0; c < NAH; ++c) async16(gA[c], As + c * 2048 + tid * 8);
#pragma unroll
    for (int c = 0; c < NBH; ++c) async16(gB[c], Bs + c * 2048 + tid * 8);
#pragma unroll
    for (int c = 0; c < NAH; ++c) gA[c] += 32;
#pragma unroll
    for (int c = 0; c < NBH; ++c) gB[c] += 32;
    __syncthreads();
    bf16x8 af[4], bfv[NFB];
#pragma unroll
    for (int r = 0; r < 4; ++r) af[r] = *(const bf16x8*)(aBase + r * 512 + colsel);
#pragma unroll
    for (int c = 0; c < NFB; ++c) bfv[c] = *(const bf16x8*)(bBase + c * 512 + colsel);
#pragma unroll
    for (int r = 0; r < 4; ++r)
#pragma unroll
      for (int c = 0; c < NFB; ++c)
        acc[r][c] = __builtin_amdgcn_mfma_f32_16x16x32_bf16(af[r], bfv[c], acc[r][c], 0, 0, 0);
    __syncthreads();
  }
}

DEVFN int swz_scol(int tid) { return (((tid & 3) ^ ((tid >> 3) & 3)) * 8); }
DEVFN int swz_colsel(int quad, int l15) { return ((quad ^ ((l15 >> 1) & 3)) * 8); }

// ---------------------------------------------------------------------------
// prep: all transposes/converts/bias-concat/bucket-bookkeeping in ONE launch
DEVFN void transpose_tile(const float* src, bf16* dst, int R, int C, int bx, int by) {
  __shared__ float tile[32][33];
  const int c0 = bx * 32, r0 = by * 32;
  const int tx = threadIdx.x & 31, ty = threadIdx.x >> 5;
#pragma unroll
  for (int rr = ty; rr < 32; rr += 8)
    tile[rr][tx] = src[(size_t)(r0 + rr) * C + c0 + tx];
  __syncthreads();
#pragma unroll
  for (int rr = ty; rr < 32; rr += 8)
    dst[(size_t)(c0 + rr) * R + r0 + tx] = __float2bfloat16(tile[tx][rr]);
}

__global__ __launch_bounds__(256) void prep_all_k(
    const float* __restrict__ x, bf16* __restrict__ xb,
    const float* __restrict__ yw0, const float* __restrict__ dw0,
    const float* __restrict__ zw0, const float* __restrict__ tw0,
    bf16* __restrict__ BtL1,
    const float* __restrict__ yw1, const float* __restrict__ dw1,
    const float* __restrict__ zw1, bf16* __restrict__ BtL2,
    const float* __restrict__ tw1, bf16* __restrict__ tw1t,
    const float* __restrict__ zhW, bf16* __restrict__ zhWt,
    const float* __restrict__ yb0, const float* __restrict__ db0,
    const float* __restrict__ zb0, const float* __restrict__ tb0,
    const float* __restrict__ yb1, const float* __restrict__ db1,
    const float* __restrict__ zb1,
    float* __restrict__ biasAll, float* __restrict__ r0All,
    float* __restrict__ r1All, float* __restrict__ biasL2,
    const int* __restrict__ t, int* __restrict__ cnt, int* __restrict__ seg,
    int* __restrict__ rank, int* __restrict__ sids) {
  int l = blockIdx.x;
  if (l < 8192) {  // x fp32 -> bf16, 8 elems/thread
    size_t i = ((size_t)l * 256 + threadIdx.x) * 8;
    float4 v0 = *(const float4*)(x + i);
    float4 v1 = *(const float4*)(x + i + 4);
    union { bf16 h[8]; uint4 u; } o;
    o.h[0] = __float2bfloat16(v0.x); o.h[1] = __float2bfloat16(v0.y);
    o.h[2] = __float2bfloat16(v0.z); o.h[3] = __float2bfloat16(v0.w);
    o.h[4] = __float2bfloat16(v1.x); o.h[5] = __float2bfloat16(v1.y);
    o.h[6] = __float2bfloat16(v1.z); o.h[7] = __float2bfloat16(v1.w);
    *(uint4*)(xb + i) = o.u;
    return;
  }
  l -= 8192;
  if (l < 4096) {  // BtL1: {yw0,dw0,zw0[2:],tw0} transposed
    int z = l >> 10, rem = l & 1023, bx = rem & 31, by = rem >> 5;
    const float* src = (z == 0) ? yw0 : (z == 1) ? dw0 : (z == 2) ? zw0 + 2048 : tw0;
    int C = (z == 3) ? 256 : 1024;
    if (bx * 32 < C)
      transpose_tile(src, BtL1 + (size_t)z * 1024 * 1024, 1024, C, bx, by);
    return;
  }
  l -= 4096;
  if (l < 3072) {  // BtL2: {yw1,dw1,zw1} transposed
    int z = l >> 10, rem = l & 1023, bx = rem & 31, by = rem >> 5;
    const float* src = (z == 0) ? yw1 : (z == 1) ? dw1 : zw1;
    transpose_tile(src, BtL2 + (size_t)z * 1024 * 1024, 1024, 1024, bx, by);
    return;
  }
  l -= 3072;
  if (l < 64) {  // tw1t
    transpose_tile(tw1, tw1t, 256, 256, l & 7, l >> 3);
    return;
  }
  l -= 64;
  if (l < 3584) {  // zhWt: 7 x [1024][512] -> [512][1024]
    int z = l >> 9, rem = l & 511, bx = rem & 15, by = rem >> 4;
    transpose_tile(zhW + (size_t)z * 1024 * 512, zhWt + (size_t)z * 512 * 1024,
                   1024, 512, bx, by);
    return;
  }
  l -= 3584;
  if (l < 13) {  // bias / rank-2 concat
    int i = l * 256 + threadIdx.x;
    if (i >= 3328) return;
    float b;
    if (i < 1024) b = yb0[i];
    else if (i < 2048) b = db0[i - 1024];
    else if (i < 3072) b = zb0[i - 2048];
    else b = tb0[i - 3072];
    biasAll[i] = b;
    bool inz = (i >= 2048 && i < 3072);
    r0All[i] = inz ? zw0[i - 2048] : 0.f;
    r1All[i] = inz ? zw0[1024 + (i - 2048)] : 0.f;
    if (i < 3072)
      biasL2[i] = (i < 1024) ? yb1[i] : (i < 2048) ? db1[i - 1024] : zb1[i - 2048];
    return;
  }
  {  // bucket bookkeeping: single block, 256 threads x 64 items
    __shared__ int h[8], sseg[8];
    const int tid = threadIdx.x;
    if (tid < 8) h[tid] = 0;
    __syncthreads();
    const int base = tid * 64;
    int lc[7] = {0, 0, 0, 0, 0, 0, 0};
    for (int i = 0; i < 64; ++i) lc[t[base + i]]++;
    int myoff[7];
#pragma unroll
    for (int k = 0; k < 7; ++k) myoff[k] = atomicAdd(&h[k], lc[k]);
    __syncthreads();
    if (tid == 0) {
      int s = 0;
      for (int k = 0; k < 7; ++k) { sseg[k] = s; s += h[k]; }
      sseg[7] = s;
    }
    __syncthreads();
    if (tid < 7) { cnt[tid] = h[tid]; seg[tid] = sseg[tid]; }
    if (tid == 7) seg[7] = sseg[7];
    int cur[7];
#pragma unroll
    for (int k = 0; k < 7; ++k) cur[k] = sseg[k] + myoff[k];
    for (int i = 0; i < 64; ++i) {
      int b = base + i, k = t[b];
      int r = cur[k]++;
      rank[b] = r;
      sids[r] = b;
    }
  }
}

// ---------------------------------------------------------------------------
// fused layer-1: [16384,1024] x [1024,3328] -> {a1y,a1d,a1z,ht1}
// 256x256 8-phase core; XCD-contiguous m-bands (832 = 8 xcd x 8 m x 13 n).
__global__ __launch_bounds__(512, 1) void gemm_l1_k(
    const bf16* __restrict__ A, const bf16* __restrict__ Bt,
    const float* __restrict__ biasAll, const float* __restrict__ r0All,
    const float* __restrict__ r1All, const float* __restrict__ yv,
    const float* __restrict__ dv, bf16* __restrict__ a1y,
    bf16* __restrict__ a1d, bf16* __restrict__ a1z, bf16* __restrict__ ht1) {
  __shared__ bf16 lds[65536];  // 128 KiB
  const int tid = threadIdx.x, lane = tid & 63, wid = tid >> 6;
  const int wm = wid >> 2, wn = wid & 3, quad = lane >> 4, l15 = lane & 15;
  const int id = blockIdx.x;
  const int xcd = id & 7, lid = id >> 3;             // lid in [0,104)
  const int mt = xcd * 8 + (lid & 7), nt = lid >> 3; // mt<64, nt<13
  const int bm0 = mt * 256, bn0 = nt * 256;
  const int srow = tid >> 3, scol = ((tid & 7) ^ ((tid >> 3) & 7)) * 8;
  const bf16* pA = A + (size_t)(bm0 + srow) * 1024 + scol;
  const bf16* pB = Bt + (size_t)(bn0 + srow) * 1024 + scol;
  f32x4 acc[8][4] = {};
  gemm256(pA, pB, 1024, 1024, 16, lds, tid, wm, wn, quad, l15, acc);

  const int g = nt >> 2;
  bf16* dst = (g == 0) ? a1y : (g == 1) ? a1d : (g == 2) ? a1z : ht1;
  const int ldc = (g == 3) ? 256 : 1024;
  const int colb = bn0 - g * 1024;
  float bv[4], z0[4], z1[4];
#pragma unroll
  for (int nf = 0; nf < 4; ++nf) {
    int gn = bn0 + wn * 64 + nf * 16 + l15;
    bv[nf] = biasAll[gn]; z0[nf] = r0All[gn]; z1[nf] = r1All[gn];
  }
#pragma unroll
  for (int mf = 0; mf < 8; ++mf) {
    const int rbase = bm0 + wm * 128 + mf * 16 + quad * 4;
    const float4 y4 = *(const float4*)(yv + rbase);
    const float4 d4 = *(const float4*)(dv + rbase);
#pragma unroll
    for (int q = 0; q < 4; ++q) {
      const float yy = (&y4.x)[q], dd = (&d4.x)[q];
      const size_t ro = (size_t)(rbase + q) * ldc + colb + wn * 64;
#pragma unroll
      for (int nf = 0; nf < 4; ++nf) {
        float v = acc[mf][nf][q] + bv[nf] + yy * z0[nf] + dd * z1[nf];
        dst[ro + nf * 16 + l15] = __float2bfloat16(eluf(v));
      }
    }
  }
}

// fused layer-2 + t-layer-2: blocks [0,768) = y1|d1|z1 (K=1024, XCD bands),
// blocks [768,832) = t1 (K=256). hz rows written permuted via rank[].
__global__ __launch_bounds__(512, 1) void gemm_l2t_k(
    const bf16* __restrict__ a1y, const bf16* __restrict__ a1d,
    const bf16* __restrict__ a1z, const bf16* __restrict__ ht1,
    const bf16* __restrict__ BtL2, const bf16* __restrict__ tw1t,
    const float* __restrict__ biasL2, const float* __restrict__ tb1,
    bf16* __restrict__ hyd, bf16* __restrict__ hzg, bf16* __restrict__ ht2,
    const int* __restrict__ rank) {
  __shared__ bf16 lds[65536];
  const int tid = threadIdx.x, lane = tid & 63, wid = tid >> 6;
  const int wm = wid >> 2, wn = wid & 3, quad = lane >> 4, l15 = lane & 15;
  const int id = blockIdx.x;
  int bm0, bn0, Ka, g;
  const bf16 *Aptr, *Bptr;
  if (id < 768) {
    const int xcd = id & 7, lid = id >> 3;             // lid in [0,96)
    const int mt = xcd * 8 + (lid & 7), nt = lid >> 3; // mt<64, nt<12
    bm0 = mt * 256; bn0 = nt * 256; Ka = 1024;
    g = nt >> 2;
    Aptr = (g == 0) ? a1y : (g == 1) ? a1d : a1z;
    Bptr = BtL2;
  } else {
    const int local = id - 768;  // [0,64)
    bm0 = local * 256; bn0 = 0; Ka = 256;
    g = 3; Aptr = ht1; Bptr = tw1t;
  }
  const int srow = tid >> 3, scol = ((tid & 7) ^ ((tid >> 3) & 7)) * 8;
  const bf16* pA = Aptr + (size_t)(bm0 + srow) * Ka + scol;
  const bf16* pB = Bptr + (size_t)(bn0 + srow) * Ka + scol;
  f32x4 acc[8][4] = {};
  gemm256(pA, pB, Ka, Ka, Ka >> 6, lds, tid, wm, wn, quad, l15, acc);

  const float* bias = (g == 3) ? tb1 : biasL2;
  float bv[4];
#pragma unroll
  for (int nf = 0; nf < 4; ++nf) bv[nf] = bias[bn0 + wn * 64 + nf * 16 + l15];
#pragma unroll
  for (int mf = 0; mf < 8; ++mf) {
#pragma unroll
    for (int q = 0; q < 4; ++q) {
      const int gm = bm0 + wm * 128 + mf * 16 + quad * 4 + q;
      bf16* dst; size_t rowoff;
      if (g == 2) { dst = hzg; rowoff = (size_t)rank[gm] * 1024 + (size_t)(bn0 - 2048); }
      else if (g == 3) { dst = ht2; rowoff = (size_t)gm * 256; }
      else { dst = hyd; rowoff = (size_t)gm * 2048 + bn0; }
#pragma unroll
      for (int nf = 0; nf < 4; ++nf) {
        float v = acc[mf][nf][q] + bv[nf];
        dst[rowoff + wn * 64 + nf * 16 + l15] = __float2bfloat16(eluf(v));
      }
    }
  }
}

// ---------------------------------------------------------------------------
// merged tail: z-head bucketed GEMM (blocks < ZB) + y/d heads + t-logits.
#define ZMT 28  // max m-tiles per bucket (covers 3584 rows; mean 2341, +27 sigma)
#define ZB (7 * ZMT * 8)
__global__ __launch_bounds__(256) void tail_k(
    const bf16* __restrict__ hzg, const bf16* __restrict__ zhWt,
    const float* __restrict__ zhb, const int* __restrict__ seg,
    const int* __restrict__ cnts, const int* __restrict__ sids,
    const bf16* __restrict__ hyd, const bf16* __restrict__ ht2,
    const int* __restrict__ t, const float* __restrict__ yhW,
    const float* __restrict__ yhb, const float* __restrict__ dhW,
    const float* __restrict__ dhb, const float* __restrict__ tw2,
    const float* __restrict__ tb2, float* __restrict__ out) {
  __shared__ bf16 As[128 * 32];  // 8 KB
  __shared__ bf16 Bs[64 * 32];   // 4 KB
  const int tid = threadIdx.x, lane = tid & 63, wid = tid >> 6;
  const int wv = wid, quad = lane >> 4, l15 = lane & 15;
  if (blockIdx.x < ZB) {
    const int kb = blockIdx.x / (ZMT * 8);
    const int r = blockIdx.x % (ZMT * 8);
    const int cnt = cnts[kb];
    const int bm0 = (r >> 3) * 128;
    if (bm0 >= cnt) return;
    const int n0 = (r & 7) * 64;
    const int wm = wid >> 1, wn = wid & 1;
    const int base = seg[kb];
    const int sr = tid >> 2, scol = swz_scol(tid);
    const bf16* gA[2];
    const bf16* gB[1];
#pragma unroll
    for (int c = 0; c < 2; ++c) {
      int rr = bm0 + c * 64 + sr;
      if (rr >= cnt) rr = cnt - 1;
      gA[c] = hzg + (size_t)(base + rr) * 1024 + scol;
    }
    gB[0] = zhWt + (size_t)kb * 512 * 1024 + (size_t)(n0 + sr) * 1024 + scol;
    const bf16* aBase = &As[(wm * 64 + l15) * 32];
    const bf16* bBase = &Bs[(wn * 32 + l15) * 32];
    const int colsel = swz_colsel(quad, l15);
    f32x4 acc[4][2] = {};
    kloop32<2, 1, 2>(gA, gB, As, Bs, tid, aBase, bBase, colsel, acc, 32);
    const float* bias = zhb + (size_t)kb * 512;
    float bv[2]; int gnn[2];
#pragma unroll
    for (int c = 0; c < 2; ++c) {
      gnn[c] = n0 + wn * 32 + c * 16 + l15;
      bv[c] = bias[gnn[c]];
    }
#pragma unroll
    for (int r2 = 0; r2 < 4; ++r2)
#pragma unroll
      for (int q = 0; q < 4; ++q) {
        int lm = bm0 + wm * 64 + r2 * 16 + quad * 4 + q;
        if (lm < cnt) {
          int gm = sids[base + lm];
          size_t ob = (size_t)gm * 523 + 11;
#pragma unroll
          for (int c = 0; c < 2; ++c) {
            float v = acc[r2][c][q] + bv[c];
            int n = gnn[c];
            out[ob + n] = (n < 256) ? fminf(fmaxf(v, -100.f), 100.f)
                                    : fminf(softplusf(v) + 0.001f, 100.f);
          }
        }
      }
    return;
  }
  const int hid = blockIdx.x - ZB;
  if (hid < 4096) {  // y/d heads
    const int b = hid * 4 + wv;
    const int tb = t[b];
    const float* yW = yhW + (size_t)tb * 2048;
    const float* dW = dhW + (size_t)tb * 2048;
    float s0 = 0.f, s1 = 0.f, s2 = 0.f, s3 = 0.f;
    for (int i = lane; i < 1024; i += 64) {
      float a = __bfloat162float(hyd[(size_t)b * 2048 + i]);
      float c = __bfloat162float(hyd[(size_t)b * 2048 + 1024 + i]);
      s0 += a * yW[2 * i]; s1 += a * yW[2 * i + 1];
      s2 += c * dW[2 * i]; s3 += c * dW[2 * i + 1];
    }
#pragma unroll
    for (int off = 32; off > 0; off >>= 1) {
      s0 += __shfl_down(s0, off); s1 += __shfl_down(s1, off);
      s2 += __shfl_down(s2, off); s3 += __shfl_down(s3, off);
    }
    if (lane == 0) {
      size_t o = (size_t)b * 523;
      out[o + 7] = fminf(fmaxf(s0 + yhb[tb * 2], -1e6f), 1e6f);
      out[o + 8] = fminf(softplusf(s1 + yhb[tb * 2 + 1]) + 1e-3f, 1e6f);
      out[o + 9] = fminf(fmaxf(s2 + dhb[tb * 2], -1e6f), 1e6f);
      out[o + 10] = fminf(softplusf(s3 + dhb[tb * 2 + 1]) + 1e-3f, 1e6f);
    }
  } else {  // t logits
    const int b = (hid - 4096) * 4 + wv;
    float h[4];
#pragma unroll
    for (int j = 0; j < 4; ++j)
      h[j] = __bfloat162float(ht2[(size_t)b * 256 + lane * 4 + j]);
    float pp[7];
#pragma unroll
    for (int kk = 0; kk < 7; ++kk) {
      float s = 0.f;
#pragma unroll
      for (int j = 0; j < 4; ++j) s += h[j] * tw2[(lane * 4 + j) * 7 + kk];
      pp[kk] = s;
    }
#pragma unroll
    for (int kk = 0; kk < 7; ++kk)
#pragma unroll
      for (int off = 32; off > 0; off >>= 1) pp[kk] += __shfl_down(pp[kk], off);
    if (lane == 0) {
#pragma unroll
      for (int kk = 0; kk < 7; ++kk) {
        float v = eluf(pp[kk] + tb2[kk]);
        out[(size_t)b * 523 + kk] = fminf(fmaxf(v, -10.f), 10.f);
      }
    }
  }
}

// ---------------------------------------------------------------------------
extern "C" void kernel_launch(void* const* d_in, const int* in_sizes, int n_in,
                              void* d_out, int out_size, void* d_ws, size_t ws_size,
                              hipStream_t stream) {
  const float* x   = (const float*)d_in[0];
  const int*   t   = (const int*)d_in[1];
  const float* yv  = (const float*)d_in[2];
  const float* dv  = (const float*)d_in[3];
  const float* tw0 = (const float*)d_in[4];
  const float* tb0 = (const float*)d_in[5];
  const float* tw1 = (const float*)d_in[6];
  const float* tb1 = (const float*)d_in[7];
  const float* tw2 = (const float*)d_in[8];
  const float* tb2 = (const float*)d_in[9];
  const float* yw0 = (const float*)d_in[10];
  const float* yb0 = (const float*)d_in[11];
  const float* yw1 = (const float*)d_in[12];
  const float* yb1 = (const float*)d_in[13];
  const float* yhW = (const float*)d_in[14];
  const float* yhb = (const float*)d_in[15];
  const float* dw0 = (const float*)d_in[16];
  const float* db0 = (const float*)d_in[17];
  const float* dw1 = (const float*)d_in[18];
  const float* db1 = (const float*)d_in[19];
  const float* dhW = (const float*)d_in[20];
  const float* dhb = (const float*)d_in[21];
  const float* zw0 = (const float*)d_in[22];
  const float* zb0 = (const float*)d_in[23];
  const float* zw1 = (const float*)d_in[24];
  const float* zb1 = (const float*)d_in[25];
  const float* zhW = (const float*)d_in[26];
  const float* zhb = (const float*)d_in[27];
  float* out = (float*)d_out;

  const int B = 16384;
  char* p = (char*)d_ws;
  auto take = [&](size_t bytes) {
    char* r = p;
    p += (bytes + 255) & ~(size_t)255;
    return r;
  };
  bf16*  BtL1    = (bf16*)take((size_t)3328 * 1024 * 2);
  bf16*  BtL2    = (bf16*)take((size_t)3072 * 1024 * 2);
  bf16*  tw1t    = (bf16*)take((size_t)256 * 256 * 2);
  bf16*  zhWt    = (bf16*)take((size_t)7 * 512 * 1024 * 2);
  float* biasAll = (float*)take(3328 * 4);
  float* r0All   = (float*)take(3328 * 4);
  float* r1All   = (float*)take(3328 * 4);
  float* biasL2  = (float*)take(3072 * 4);
  int*   cnt     = (int*)take(8 * 4);
  int*   seg     = (int*)take(8 * 4);
  int*   rank    = (int*)take((size_t)B * 4);
  int*   sids    = (int*)take((size_t)B * 4);
  bf16*  xb      = (bf16*)take((size_t)B * 1024 * 2);  // reused as hzg after L1
  bf16*  a1y     = (bf16*)take((size_t)B * 1024 * 2);
  bf16*  a1d     = (bf16*)take((size_t)B * 1024 * 2);
  bf16*  a1z     = (bf16*)take((size_t)B * 1024 * 2);
  bf16*  ht1     = (bf16*)take((size_t)B * 256 * 2);
  bf16*  hyd     = (bf16*)take((size_t)B * 2048 * 2);
  bf16*  ht2     = (bf16*)take((size_t)B * 256 * 2);
  bf16*  hzg     = xb;

  prep_all_k<<<19022, 256, 0, stream>>>(x, xb, yw0, dw0, zw0, tw0, BtL1,
                                        yw1, dw1, zw1, BtL2, tw1, tw1t, zhW, zhWt,
                                        yb0, db0, zb0, tb0, yb1, db1, zb1,
                                        biasAll, r0All, r1All, biasL2,
                                        t, cnt, seg, rank, sids);
  gemm_l1_k<<<832, 512, 0, stream>>>(xb, BtL1, biasAll, r0All, r1All,
                                     yv, dv, a1y, a1d, a1z, ht1);
  gemm_l2t_k<<<832, 512, 0, stream>>>(a1y, a1d, a1z, ht1, BtL2, tw1t,
                                      biasL2, tb1, hyd, hzg, ht2, rank);
  tail_k<<<ZB + 8192, 256, 0, stream>>>(hzg, zhWt, zhb, seg, cnt, sids,
                                        hyd, ht2, t, yhW, yhb, dhW, dhb,
                                        tw2, tb2, out);
}